// Round 2
// baseline (11083.407 us; speedup 1.0000x reference)
//
#include <hip/hip_runtime.h>
#include <hip/hip_bf16.h>
#include <hip/hip_cooperative_groups.h>

namespace cg = cooperative_groups;

// Bidirectional GRU encoder, MI355X gfx950.
// Phase 1: prep (transpose+cast weights, gather embeddings) + one big MFMA GEMM xW = A @ Wcat.
// Phase 2: ONE persistent cooperative kernel runs all 256 steps; U is register-resident,
//          h exchanged via global + grid.sync().

typedef __attribute__((ext_vector_type(8))) short bf16x8;   // 8 x bf16 (4 VGPRs)
typedef __attribute__((ext_vector_type(4))) float f32x4;    // MFMA accumulator

__device__ __forceinline__ f32x4 mfma_bf16(bf16x8 a, bf16x8 b, f32x4 c) {
  return __builtin_amdgcn_mfma_f32_16x16x32_bf16(a, b, c, 0, 0, 0);
}

// ---------------- prep kernels ----------------

// dst[c][r] = (bf16)src[r][c];  src: [R][C] f32 row-major, dst: [C][R] bf16 row-major
__global__ __launch_bounds__(256) void transpose_cast(const float* __restrict__ src,
                                                      __hip_bfloat16* __restrict__ dst,
                                                      int R, int C) {
  __shared__ float tile[32][33];
  const int tid = threadIdx.x;
  const int bc = blockIdx.x * 32;   // col block of src
  const int br = blockIdx.y * 32;   // row block of src
#pragma unroll
  for (int i = 0; i < 4; ++i) {
    int idx = tid + i * 256;
    int r = idx >> 5, c = idx & 31;
    tile[r][c] = src[(size_t)(br + r) * C + bc + c];
  }
  __syncthreads();
#pragma unroll
  for (int i = 0; i < 4; ++i) {
    int idx = tid + i * 256;
    int r = idx >> 5, c = idx & 31;
    dst[(size_t)(bc + r) * R + br + c] = __float2bfloat16(tile[c][r]);
  }
}

// A[t*32+b][e] = (bf16) emb[x[b][t]][e];  A: [8192][512] bf16
__global__ __launch_bounds__(256) void gather_embed(const int* __restrict__ x,
                                                    const float* __restrict__ emb,
                                                    __hip_bfloat16* __restrict__ A) {
  int ch = blockIdx.x * 256 + threadIdx.x;      // [0, 8192*64)
  int row = ch >> 6, seg = ch & 63;
  int b = row & 31, t = row >> 5;
  int idx = x[b * 256 + t];
  const float* s = emb + (size_t)idx * 512 + seg * 8;
  float4 f0 = *(const float4*)(s);
  float4 f1 = *(const float4*)(s + 4);
  __hip_bfloat16 h[8];
  h[0] = __float2bfloat16(f0.x); h[1] = __float2bfloat16(f0.y);
  h[2] = __float2bfloat16(f0.z); h[3] = __float2bfloat16(f0.w);
  h[4] = __float2bfloat16(f1.x); h[5] = __float2bfloat16(f1.y);
  h[6] = __float2bfloat16(f1.z); h[7] = __float2bfloat16(f1.w);
  *(uint4*)(A + (size_t)row * 512 + seg * 8) = *(const uint4*)h;
}

// H16 buffer0 init from h0
__global__ __launch_bounds__(256) void init_h(const float* __restrict__ h0f,
                                              const float* __restrict__ h0b,
                                              __hip_bfloat16* __restrict__ h16) {
  int i = blockIdx.x * 256 + threadIdx.x;   // [0, 65536)
  int d = i >> 15, j = i & 32767;
  float v = d ? h0b[j] : h0f[j];
  h16[i] = __float2bfloat16(v);
}

// ---------------- big GEMM: xW[8192][6144] = A[8192][512] @ WT[6144][512]^T ----------------
__global__ __launch_bounds__(256) void gemm_xw(const __hip_bfloat16* __restrict__ A,
                                               const __hip_bfloat16* __restrict__ B,
                                               __hip_bfloat16* __restrict__ C) {
  __shared__ char sm[2 * 128 * 80];
  const int tid = threadIdx.x;
  const int bn = blockIdx.x, bm = blockIdx.y;
  const int l = tid & 63, w = tid >> 6;
  const int wm = w & 1, wn = w >> 1;
  const int lr = l & 15, lk = l >> 4;
  f32x4 acc[4][4] = {};
  for (int k0 = 0; k0 < 512; k0 += 32) {
    __syncthreads();
#pragma unroll
    for (int i = 0; i < 2; ++i) {
      int ch = tid + i * 256;
      int row = ch >> 2, kq = ch & 3;
      uint4 va = *(const uint4*)(A + (size_t)(bm * 128 + row) * 512 + k0 + kq * 8);
      *(uint4*)(sm + row * 80 + kq * 16) = va;
      uint4 vb = *(const uint4*)(B + (size_t)(bn * 128 + row) * 512 + k0 + kq * 8);
      *(uint4*)(sm + 10240 + row * 80 + kq * 16) = vb;
    }
    __syncthreads();
    bf16x8 af[4], bfr[4];
#pragma unroll
    for (int m = 0; m < 4; ++m)
      af[m] = *(const bf16x8*)(sm + (wm * 64 + m * 16 + lr) * 80 + lk * 16);
#pragma unroll
    for (int n = 0; n < 4; ++n)
      bfr[n] = *(const bf16x8*)(sm + 10240 + (wn * 64 + n * 16 + lr) * 80 + lk * 16);
#pragma unroll
    for (int m = 0; m < 4; ++m)
#pragma unroll
      for (int n = 0; n < 4; ++n)
        acc[m][n] = mfma_bf16(af[m], bfr[n], acc[m][n]);
  }
#pragma unroll
  for (int m = 0; m < 4; ++m)
#pragma unroll
    for (int n = 0; n < 4; ++n)
#pragma unroll
      for (int v = 0; v < 4; ++v) {
        int row = bm * 128 + wm * 64 + m * 16 + lk * 4 + v;
        int col = bn * 128 + wn * 64 + n * 16 + lr;
        C[(size_t)row * 6144 + col] = __float2bfloat16(acc[m][n][v]);
      }
}

// ---------------- persistent GRU recurrence ----------------
// grid = 128 blocks: blockIdx.x = colblk*2 + dir. 384 threads = 6 waves:
// wave w -> (m = w&1 batch-half, g = w>>1 gate). Each wave holds its U fragments
// (16 cols x K=1024 for gate g) in 128 VGPRs for the whole kernel.
// h state: f32 in registers of the g==0 (combine) wave; bf16 broadcast via global.
__global__ __launch_bounds__(384, 2) void gru_persist(
    const __hip_bfloat16* __restrict__ xW,
    const __hip_bfloat16* __restrict__ UT,
    const float* __restrict__ bias_f,
    const float* __restrict__ bias_b,
    const float* __restrict__ h0_f,
    const float* __restrict__ h0_b,
    __hip_bfloat16* H16,        // [2 buffers][2 dirs][32][1024]
    float* __restrict__ out) {
  __shared__ float xacc[2][2][16][17];   // [m][g-1][b_local][col(+pad)]

  const int tid = threadIdx.x;
  const int l = tid & 63, w = tid >> 6;
  const int m = w & 1, g = w >> 1;
  const int dir = blockIdx.x & 1;
  const int c0 = (blockIdx.x >> 1) * 16;
  const int lr = l & 15, lk = l >> 4;
  const int col = c0 + lr;

  // register-resident U fragments: gate g, cols c0..c0+15, all K
  bf16x8 ub[32];
  {
    const __hip_bfloat16* Urow =
        UT + (size_t)(dir * 3072 + g * 1024 + col) * 1024 + lk * 8;
#pragma unroll
    for (int k = 0; k < 32; ++k)
      ub[k] = *(const bf16x8*)(Urow + k * 32);
  }

  const float* bias = dir ? bias_b : bias_f;
  const float b0z = bias[col],        b0r = bias[1024 + col], b0n = bias[2048 + col];
  const float b1z = bias[3072 + col], b1r = bias[4096 + col], b1n = bias[5120 + col];

  // persistent f32 h for this lane's output tile (combine wave only uses it)
  float hp[4];
  {
    const float* h0 = dir ? h0_b : h0_f;
#pragma unroll
    for (int v = 0; v < 4; ++v)
      hp[v] = h0[(m * 16 + lk * 4 + v) * 1024 + col];
  }

  cg::grid_group grid = cg::this_grid();

  for (int s = 0; s < 256; ++s) {
    const __hip_bfloat16* hin  = H16 + (size_t)(s & 1) * 65536 + dir * 32768;
    __hip_bfloat16*       hout = H16 + (size_t)((s & 1) ^ 1) * 65536 + dir * 32768;

    // hU for gate g: [16 batch x 16 cols], K=1024 in 32 chunks, 4 acc chains
    f32x4 a0 = {}, a1 = {}, a2 = {}, a3 = {};
    const __hip_bfloat16* hrow = hin + (size_t)(m * 16 + lr) * 1024 + lk * 8;
#pragma unroll
    for (int k = 0; k < 32; k += 4) {
      bf16x8 A0 = *(const bf16x8*)(hrow + (k + 0) * 32);
      bf16x8 A1 = *(const bf16x8*)(hrow + (k + 1) * 32);
      bf16x8 A2 = *(const bf16x8*)(hrow + (k + 2) * 32);
      bf16x8 A3 = *(const bf16x8*)(hrow + (k + 3) * 32);
      a0 = mfma_bf16(A0, ub[k + 0], a0);
      a1 = mfma_bf16(A1, ub[k + 1], a1);
      a2 = mfma_bf16(A2, ub[k + 2], a2);
      a3 = mfma_bf16(A3, ub[k + 3], a3);
    }
    f32x4 acc = (a0 + a1) + (a2 + a3);

    if (g) {
#pragma unroll
      for (int v = 0; v < 4; ++v)
        xacc[m][g - 1][lk * 4 + v][lr] = acc[v];
    }
    __syncthreads();
    if (!g) {
      const int t = dir ? (255 - s) : s;
#pragma unroll
      for (int v = 0; v < 4; ++v) {
        const int b = m * 16 + lk * 4 + v;
        const float hUz = acc[v] + b1z;
        const float hUr = xacc[m][0][lk * 4 + v][lr] + b1r;
        const float hUn = xacc[m][1][lk * 4 + v][lr] + b1n;
        const size_t xb = (size_t)(t * 32 + b) * 6144 + dir * 3072 + col;
        const float xz = __bfloat162float(xW[xb]);
        const float xr = __bfloat162float(xW[xb + 1024]);
        const float xn = __bfloat162float(xW[xb + 2048]);
        const float z = 1.f / (1.f + expf(-(xz + b0z + hUz)));
        const float r = 1.f / (1.f + expf(-(xr + b0r + hUr)));
        const float n = tanhf(xn + b0n + r * hUn);
        const float hn = z * hp[v] + (1.f - z) * n;
        hp[v] = hn;
        out[((size_t)b * 256 + t) * 2048 + dir * 1024 + col] = hn;
        hout[(size_t)b * 1024 + col] = __float2bfloat16(hn);
        if (s == 255) out[16777216 + dir * 32768 + b * 1024 + col] = hn;
      }
      __threadfence();   // release h writes to device scope
    }
    grid.sync();
    __threadfence();     // acquire: don't serve stale h from local caches
  }
}

// ---------------- host ----------------

extern "C" void kernel_launch(void* const* d_in, const int* in_sizes, int n_in,
                              void* d_out, int out_size, void* d_ws, size_t ws_size,
                              hipStream_t stream) {
  const int*   x    = (const int*)d_in[0];
  const float* emb  = (const float*)d_in[1];
  const float* W_f  = (const float*)d_in[2];
  const float* U_f  = (const float*)d_in[3];
  const float* b_f  = (const float*)d_in[4];
  const float* W_b  = (const float*)d_in[5];
  const float* U_b  = (const float*)d_in[6];
  const float* b_b  = (const float*)d_in[7];
  const float* h0_f = (const float*)d_in[8];
  const float* h0_b = (const float*)d_in[9];
  float* out = (float*)d_out;
  char* ws = (char*)d_ws;

  const size_t SZ_A  = (size_t)8192 * 512 * 2;
  const size_t SZ_WT = (size_t)6144 * 512 * 2;
  const size_t SZ_UT = (size_t)6144 * 1024 * 2;
  const size_t SZ_XW = (size_t)8192 * 6144 * 2;

  __hip_bfloat16* A   = (__hip_bfloat16*)(ws);
  __hip_bfloat16* WT  = (__hip_bfloat16*)(ws + SZ_A);
  __hip_bfloat16* UT  = (__hip_bfloat16*)(ws + SZ_A + SZ_WT);
  __hip_bfloat16* XW  = (__hip_bfloat16*)(ws + SZ_A + SZ_WT + SZ_UT);
  __hip_bfloat16* H16 = (__hip_bfloat16*)(ws + SZ_A + SZ_WT + SZ_UT + SZ_XW);

  // prep
  transpose_cast<<<dim3(96, 16), 256, 0, stream>>>(W_f, WT, 512, 3072);
  transpose_cast<<<dim3(96, 16), 256, 0, stream>>>(W_b, WT + (size_t)3072 * 512, 512, 3072);
  transpose_cast<<<dim3(96, 32), 256, 0, stream>>>(U_f, UT, 1024, 3072);
  transpose_cast<<<dim3(96, 32), 256, 0, stream>>>(U_b, UT + (size_t)3072 * 1024, 1024, 3072);
  gather_embed<<<2048, 256, 0, stream>>>(x, emb, A);
  init_h<<<256, 256, 0, stream>>>(h0_f, h0_b, H16);

  // xW = A @ WT^T
  gemm_xw<<<dim3(48, 64), 256, 0, stream>>>(A, WT, XW);

  // persistent recurrence: one cooperative launch, 256 grid-synced steps
  void* args[] = {(void*)&XW, (void*)&UT, (void*)&b_f, (void*)&b_b,
                  (void*)&h0_f, (void*)&h0_b, (void*)&H16, (void*)&out};
  hipLaunchCooperativeKernel((void*)gru_persist, dim3(128), dim3(384),
                             args, 0, stream);
}

// Round 3
// 2378.264 us; speedup vs baseline: 4.6603x; 4.6603x over previous
//
#include <hip/hip_runtime.h>
#include <hip/hip_bf16.h>

// Bidirectional GRU encoder, MI355X gfx950.
// Phase 1: prep + one big MFMA GEMM xW = A @ Wcat.
// Phase 2: ONE persistent kernel (cooperative launch for residency guarantee only),
//          hand-rolled relaxed-atomic barrier, sc0/sc1 coherent h exchange,
//          U pinned in VGPRs via inline-asm loads (non-rematerializable).

typedef __attribute__((ext_vector_type(8))) short bf16x8;   // 8 x bf16 (4 VGPRs)
typedef __attribute__((ext_vector_type(4))) float f32x4;    // MFMA accumulator

__device__ __forceinline__ f32x4 mfma_bf16(bf16x8 a, bf16x8 b, f32x4 c) {
  return __builtin_amdgcn_mfma_f32_16x16x32_bf16(a, b, c, 0, 0, 0);
}

// plain 16B global load (asm: value can't be rematerialized -> stays in VGPRs)
__device__ __forceinline__ bf16x8 ld_b128(const __hip_bfloat16* p) {
  bf16x8 r;
  asm volatile("global_load_dwordx4 %0, %1, off" : "=v"(r) : "v"(p));
  return r;
}
// device-coherent 16B load (bypass L1/L2, read from coherence point)
__device__ __forceinline__ bf16x8 ld_sys_b128(const __hip_bfloat16* p) {
  bf16x8 r;
  asm volatile("global_load_dwordx4 %0, %1, off sc0 sc1" : "=v"(r) : "v"(p));
  return r;
}
// plain u16 load (zero-extended)
__device__ __forceinline__ unsigned ld_u16(const __hip_bfloat16* p) {
  unsigned r;
  asm volatile("global_load_ushort %0, %1, off" : "=v"(r) : "v"(p));
  return r;
}
// device-coherent 2B store
__device__ __forceinline__ void st_sys_u16(__hip_bfloat16* p, unsigned v) {
  asm volatile("global_store_short %0, %1, off sc0 sc1" :: "v"(p), "v"(v) : "memory");
}

__device__ __forceinline__ float bf2f(unsigned u) {
  return __uint_as_float(u << 16);
}

// ---------------- prep kernels ----------------

__global__ __launch_bounds__(256) void transpose_cast(const float* __restrict__ src,
                                                      __hip_bfloat16* __restrict__ dst,
                                                      int R, int C) {
  __shared__ float tile[32][33];
  const int tid = threadIdx.x;
  const int bc = blockIdx.x * 32;
  const int br = blockIdx.y * 32;
#pragma unroll
  for (int i = 0; i < 4; ++i) {
    int idx = tid + i * 256;
    int r = idx >> 5, c = idx & 31;
    tile[r][c] = src[(size_t)(br + r) * C + bc + c];
  }
  __syncthreads();
#pragma unroll
  for (int i = 0; i < 4; ++i) {
    int idx = tid + i * 256;
    int r = idx >> 5, c = idx & 31;
    dst[(size_t)(bc + r) * R + br + c] = __float2bfloat16(tile[c][r]);
  }
}

__global__ __launch_bounds__(256) void gather_embed(const int* __restrict__ x,
                                                    const float* __restrict__ emb,
                                                    __hip_bfloat16* __restrict__ A) {
  int ch = blockIdx.x * 256 + threadIdx.x;
  int row = ch >> 6, seg = ch & 63;
  int b = row & 31, t = row >> 5;
  int idx = x[b * 256 + t];
  const float* s = emb + (size_t)idx * 512 + seg * 8;
  float4 f0 = *(const float4*)(s);
  float4 f1 = *(const float4*)(s + 4);
  __hip_bfloat16 h[8];
  h[0] = __float2bfloat16(f0.x); h[1] = __float2bfloat16(f0.y);
  h[2] = __float2bfloat16(f0.z); h[3] = __float2bfloat16(f0.w);
  h[4] = __float2bfloat16(f1.x); h[5] = __float2bfloat16(f1.y);
  h[6] = __float2bfloat16(f1.z); h[7] = __float2bfloat16(f1.w);
  *(uint4*)(A + (size_t)row * 512 + seg * 8) = *(const uint4*)h;
}

__global__ __launch_bounds__(256) void init_h(const float* __restrict__ h0f,
                                              const float* __restrict__ h0b,
                                              __hip_bfloat16* __restrict__ h16,
                                              unsigned* __restrict__ bar) {
  int i = blockIdx.x * 256 + threadIdx.x;
  int d = i >> 15, j = i & 32767;
  float v = d ? h0b[j] : h0f[j];
  h16[i] = __float2bfloat16(v);
  if (i == 0) bar[0] = 0u;
}

// ---------------- big GEMM: xW[8192][6144] = A[8192][512] @ WT[6144][512]^T ----------------
__global__ __launch_bounds__(256) void gemm_xw(const __hip_bfloat16* __restrict__ A,
                                               const __hip_bfloat16* __restrict__ B,
                                               __hip_bfloat16* __restrict__ C) {
  __shared__ char sm[2 * 128 * 80];
  const int tid = threadIdx.x;
  const int bn = blockIdx.x, bm = blockIdx.y;
  const int l = tid & 63, w = tid >> 6;
  const int wm = w & 1, wn = w >> 1;
  const int lr = l & 15, lk = l >> 4;
  f32x4 acc[4][4] = {};
  for (int k0 = 0; k0 < 512; k0 += 32) {
    __syncthreads();
#pragma unroll
    for (int i = 0; i < 2; ++i) {
      int ch = tid + i * 256;
      int row = ch >> 2, kq = ch & 3;
      uint4 va = *(const uint4*)(A + (size_t)(bm * 128 + row) * 512 + k0 + kq * 8);
      *(uint4*)(sm + row * 80 + kq * 16) = va;
      uint4 vb = *(const uint4*)(B + (size_t)(bn * 128 + row) * 512 + k0 + kq * 8);
      *(uint4*)(sm + 10240 + row * 80 + kq * 16) = vb;
    }
    __syncthreads();
    bf16x8 af[4], bfr[4];
#pragma unroll
    for (int m = 0; m < 4; ++m)
      af[m] = *(const bf16x8*)(sm + (wm * 64 + m * 16 + lr) * 80 + lk * 16);
#pragma unroll
    for (int n = 0; n < 4; ++n)
      bfr[n] = *(const bf16x8*)(sm + 10240 + (wn * 64 + n * 16 + lr) * 80 + lk * 16);
#pragma unroll
    for (int m = 0; m < 4; ++m)
#pragma unroll
      for (int n = 0; n < 4; ++n)
        acc[m][n] = mfma_bf16(af[m], bfr[n], acc[m][n]);
  }
#pragma unroll
  for (int m = 0; m < 4; ++m)
#pragma unroll
    for (int n = 0; n < 4; ++n)
#pragma unroll
      for (int v = 0; v < 4; ++v) {
        int row = bm * 128 + wm * 64 + m * 16 + lk * 4 + v;
        int col = bn * 128 + wn * 64 + n * 16 + lr;
        C[(size_t)row * 6144 + col] = __float2bfloat16(acc[m][n][v]);
      }
}

// ---------------- persistent GRU recurrence ----------------
// grid = 128 blocks: blockIdx.x = colblk*2 + dir; 384 threads = 6 waves:
// wave w -> (m = w&1 batch-half, g = w>>1 gate). U fragments pinned in VGPRs
// via asm loads. h exchanged via sc0/sc1 coherent ops; barrier = relaxed
// monotonic atomic counter (no fences, no cache flushes).
__global__ __launch_bounds__(384, 2) void gru_persist(
    const __hip_bfloat16* __restrict__ xW,
    const __hip_bfloat16* __restrict__ UT,
    const float* __restrict__ bias_f,
    const float* __restrict__ bias_b,
    const float* __restrict__ h0_f,
    const float* __restrict__ h0_b,
    __hip_bfloat16* H16,        // [2 buffers][2 dirs][32][1024]
    unsigned* bar,
    float* __restrict__ out) {
  __shared__ float xacc[2][2][16][17];   // [m][g-1][b_local][col(+pad)]

  const int tid = threadIdx.x;
  const int l = tid & 63, w = tid >> 6;
  const int m = w & 1, g = w >> 1;
  const int dir = blockIdx.x & 1;
  const int c0 = (blockIdx.x >> 1) * 16;
  const int lr = l & 15, lk = l >> 4;
  const int col = c0 + lr;

  // ---- pin U fragments in registers (asm loads: cannot be rematerialized) ----
  bf16x8 ub[32];
  {
    const __hip_bfloat16* Urow =
        UT + (size_t)(dir * 3072 + g * 1024 + col) * 1024 + lk * 8;
#pragma unroll
    for (int k = 0; k < 32; ++k) ub[k] = ld_b128(Urow + k * 32);
    asm volatile("s_waitcnt vmcnt(0)" ::: "memory");
    __builtin_amdgcn_sched_barrier(0);
  }

  const float* bias = dir ? bias_b : bias_f;
  const float b0z = bias[col],        b0r = bias[1024 + col], b0n = bias[2048 + col];
  const float b1z = bias[3072 + col], b1r = bias[4096 + col], b1n = bias[5120 + col];

  float hp[4];
  {
    const float* h0 = dir ? h0_b : h0_f;
#pragma unroll
    for (int v = 0; v < 4; ++v)
      hp[v] = h0[(m * 16 + lk * 4 + v) * 1024 + col];
  }

  for (int s = 0; s < 256; ++s) {
    const __hip_bfloat16* hin  = H16 + (size_t)(s & 1) * 65536 + dir * 32768;
    __hip_bfloat16*       hout = H16 + (size_t)((s & 1) ^ 1) * 65536 + dir * 32768;
    const int t = dir ? (255 - s) : s;

    // ---- issue xW loads first (combine waves only); drained by vmcnt below ----
    unsigned xwv[12];
    if (g == 0) {
      const __hip_bfloat16* xp =
          xW + (size_t)(t * 32 + m * 16) * 6144 + dir * 3072 + col;
#pragma unroll
      for (int v = 0; v < 4; ++v)
#pragma unroll
        for (int gg = 0; gg < 3; ++gg)
          xwv[v * 3 + gg] = ld_u16(xp + (size_t)(lk * 4 + v) * 6144 + gg * 1024);
    }

    // ---- K-loop: 32 h-frags (coherent loads), 8 groups of 4, 2-deep pipeline ----
    const __hip_bfloat16* hrow = hin + (size_t)(m * 16 + lr) * 1024 + lk * 8;
    bf16x8 buf0[4], buf1[4];
    f32x4 ac0 = {}, ac1 = {};
#pragma unroll
    for (int k = 0; k < 4; ++k) buf0[k] = ld_sys_b128(hrow + k * 32);
#pragma unroll
    for (int jj = 0; jj < 4; ++jj) {
      const int je = 2 * jj;
      if (je < 7) {
#pragma unroll
        for (int k = 0; k < 4; ++k)
          buf1[k] = ld_sys_b128(hrow + ((je + 1) * 4 + k) * 32);
        asm volatile("s_waitcnt vmcnt(4)" ::: "memory");
      } else {
        asm volatile("s_waitcnt vmcnt(0)" ::: "memory");
      }
      __builtin_amdgcn_sched_barrier(0);
#pragma unroll
      for (int k = 0; k < 4; ++k) {
        if (k & 1) ac1 = mfma_bf16(buf0[k], ub[je * 4 + k], ac1);
        else       ac0 = mfma_bf16(buf0[k], ub[je * 4 + k], ac0);
      }
      const int jo = 2 * jj + 1;
      if (jo < 7) {
#pragma unroll
        for (int k = 0; k < 4; ++k)
          buf0[k] = ld_sys_b128(hrow + ((jo + 1) * 4 + k) * 32);
        asm volatile("s_waitcnt vmcnt(4)" ::: "memory");
      } else {
        asm volatile("s_waitcnt vmcnt(0)" ::: "memory");
      }
      __builtin_amdgcn_sched_barrier(0);
#pragma unroll
      for (int k = 0; k < 4; ++k) {
        if (k & 1) ac1 = mfma_bf16(buf1[k], ub[jo * 4 + k], ac1);
        else       ac0 = mfma_bf16(buf1[k], ub[jo * 4 + k], ac0);
      }
    }
    f32x4 acc = ac0 + ac1;

    // ---- gate exchange + combine ----
    if (g) {
#pragma unroll
      for (int v = 0; v < 4; ++v)
        xacc[m][g - 1][lk * 4 + v][lr] = acc[v];
    }
    __syncthreads();
    if (!g) {
#pragma unroll
      for (int v = 0; v < 4; ++v) {
        const int b = m * 16 + lk * 4 + v;
        const float xz = bf2f(xwv[v * 3 + 0]);
        const float xr = bf2f(xwv[v * 3 + 1]);
        const float xn = bf2f(xwv[v * 3 + 2]);
        const float hUz = acc[v] + b1z;
        const float hUr = xacc[m][0][lk * 4 + v][lr] + b1r;
        const float hUn = xacc[m][1][lk * 4 + v][lr] + b1n;
        const float z = 1.f / (1.f + expf(-(xz + b0z + hUz)));
        const float r = 1.f / (1.f + expf(-(xr + b0r + hUr)));
        const float n = tanhf(xn + b0n + r * hUn);
        const float hn = z * hp[v] + (1.f - z) * n;
        hp[v] = hn;
        out[((size_t)b * 256 + t) * 2048 + dir * 1024 + col] = hn;
        st_sys_u16(hout + (size_t)b * 1024 + col,
                   (unsigned)__builtin_bit_cast(unsigned short, __float2bfloat16(hn)));
        if (s == 255) out[16777216 + dir * 32768 + b * 1024 + col] = hn;
      }
    }
    // __syncthreads() drains each wave's vmcnt (incl. asm sc-stores) before s_barrier
    __syncthreads();
    if (tid == 0) {
      __hip_atomic_fetch_add(bar, 1u, __ATOMIC_RELAXED, __HIP_MEMORY_SCOPE_AGENT);
      const unsigned tgt = 128u * (unsigned)(s + 1);
      while (__hip_atomic_load(bar, __ATOMIC_RELAXED, __HIP_MEMORY_SCOPE_AGENT) < tgt)
        __builtin_amdgcn_s_sleep(2);
    }
    __syncthreads();
  }
}

// ---------------- host ----------------

extern "C" void kernel_launch(void* const* d_in, const int* in_sizes, int n_in,
                              void* d_out, int out_size, void* d_ws, size_t ws_size,
                              hipStream_t stream) {
  const int*   x    = (const int*)d_in[0];
  const float* emb  = (const float*)d_in[1];
  const float* W_f  = (const float*)d_in[2];
  const float* U_f  = (const float*)d_in[3];
  const float* b_f  = (const float*)d_in[4];
  const float* W_b  = (const float*)d_in[5];
  const float* U_b  = (const float*)d_in[6];
  const float* b_b  = (const float*)d_in[7];
  const float* h0_f = (const float*)d_in[8];
  const float* h0_b = (const float*)d_in[9];
  float* out = (float*)d_out;
  char* ws = (char*)d_ws;

  const size_t SZ_A  = (size_t)8192 * 512 * 2;
  const size_t SZ_WT = (size_t)6144 * 512 * 2;
  const size_t SZ_UT = (size_t)6144 * 1024 * 2;
  const size_t SZ_XW = (size_t)8192 * 6144 * 2;
  const size_t SZ_H  = (size_t)2 * 65536 * 2;

  __hip_bfloat16* A   = (__hip_bfloat16*)(ws);
  __hip_bfloat16* WT  = (__hip_bfloat16*)(ws + SZ_A);
  __hip_bfloat16* UT  = (__hip_bfloat16*)(ws + SZ_A + SZ_WT);
  __hip_bfloat16* XW  = (__hip_bfloat16*)(ws + SZ_A + SZ_WT + SZ_UT);
  __hip_bfloat16* H16 = (__hip_bfloat16*)(ws + SZ_A + SZ_WT + SZ_UT + SZ_XW);
  unsigned*       BAR = (unsigned*)(ws + SZ_A + SZ_WT + SZ_UT + SZ_XW + SZ_H);

  transpose_cast<<<dim3(96, 16), 256, 0, stream>>>(W_f, WT, 512, 3072);
  transpose_cast<<<dim3(96, 16), 256, 0, stream>>>(W_b, WT + (size_t)3072 * 512, 512, 3072);
  transpose_cast<<<dim3(96, 32), 256, 0, stream>>>(U_f, UT, 1024, 3072);
  transpose_cast<<<dim3(96, 32), 256, 0, stream>>>(U_b, UT + (size_t)3072 * 1024, 1024, 3072);
  gather_embed<<<2048, 256, 0, stream>>>(x, emb, A);
  init_h<<<256, 256, 0, stream>>>(h0_f, h0_b, H16, BAR);

  gemm_xw<<<dim3(48, 64), 256, 0, stream>>>(A, WT, XW);

  void* args[] = {(void*)&XW, (void*)&UT, (void*)&b_f, (void*)&b_b,
                  (void*)&h0_f, (void*)&h0_b, (void*)&H16, (void*)&BAR, (void*)&out};
  hipLaunchCooperativeKernel((void*)gru_persist, dim3(128), dim3(384),
                             args, 0, stream);
}

// Round 4
// 1349.395 us; speedup vs baseline: 8.2136x; 1.7625x over previous
//
#include <hip/hip_runtime.h>
#include <hip/hip_bf16.h>

// Bidirectional GRU encoder, MI355X gfx950.
// Phase 1: prep + one big MFMA GEMM xW = A @ Wcat.
// Phase 2: ONE persistent kernel, 128 blocks x 8 waves. Wave (m,q) owns
//          batch-half m, K-quarter q, all 3 gates: 24 U fragments pinned in
//          96 VGPRs (asm loads). Distributed per-block flag barrier (no
//          contended atomics), sc0/sc1 coherent h exchange.

typedef __attribute__((ext_vector_type(8))) short bf16x8;   // 8 x bf16 (4 VGPRs)
typedef __attribute__((ext_vector_type(4))) float f32x4;    // MFMA accumulator

__device__ __forceinline__ f32x4 mfma_bf16(bf16x8 a, bf16x8 b, f32x4 c) {
  return __builtin_amdgcn_mfma_f32_16x16x32_bf16(a, b, c, 0, 0, 0);
}

__device__ __forceinline__ bf16x8 ld_b128(const __hip_bfloat16* p) {
  bf16x8 r;
  asm volatile("global_load_dwordx4 %0, %1, off" : "=v"(r) : "v"(p));
  return r;
}
__device__ __forceinline__ bf16x8 ld_sys_b128(const __hip_bfloat16* p) {
  bf16x8 r;
  asm volatile("global_load_dwordx4 %0, %1, off sc0 sc1" : "=v"(r) : "v"(p));
  return r;
}
__device__ __forceinline__ unsigned ld_u16(const __hip_bfloat16* p) {
  unsigned r;
  asm volatile("global_load_ushort %0, %1, off" : "=v"(r) : "v"(p));
  return r;
}
__device__ __forceinline__ void st_sys_u16(__hip_bfloat16* p, unsigned v) {
  asm volatile("global_store_short %0, %1, off sc0 sc1" :: "v"(p), "v"(v) : "memory");
}
__device__ __forceinline__ void st_sys_u32(unsigned* p, unsigned v) {
  asm volatile("global_store_dword %0, %1, off sc0 sc1" :: "v"(p), "v"(v) : "memory");
}
__device__ __forceinline__ unsigned ld_sys_u32(const unsigned* p) {
  unsigned r;
  asm volatile("global_load_dword %0, %1, off sc0 sc1" : "=v"(r) : "v"(p));
  return r;
}

__device__ __forceinline__ float bf2f(unsigned u) { return __uint_as_float(u << 16); }

#define WAITV(N) asm volatile("s_waitcnt vmcnt(" #N ")" ::: "memory")

// ---------------- prep kernels ----------------

__global__ __launch_bounds__(256) void transpose_cast(const float* __restrict__ src,
                                                      __hip_bfloat16* __restrict__ dst,
                                                      int R, int C) {
  __shared__ float tile[32][33];
  const int tid = threadIdx.x;
  const int bc = blockIdx.x * 32;
  const int br = blockIdx.y * 32;
#pragma unroll
  for (int i = 0; i < 4; ++i) {
    int idx = tid + i * 256;
    int r = idx >> 5, c = idx & 31;
    tile[r][c] = src[(size_t)(br + r) * C + bc + c];
  }
  __syncthreads();
#pragma unroll
  for (int i = 0; i < 4; ++i) {
    int idx = tid + i * 256;
    int r = idx >> 5, c = idx & 31;
    dst[(size_t)(bc + r) * R + br + c] = __float2bfloat16(tile[c][r]);
  }
}

__global__ __launch_bounds__(256) void gather_embed(const int* __restrict__ x,
                                                    const float* __restrict__ emb,
                                                    __hip_bfloat16* __restrict__ A) {
  int ch = blockIdx.x * 256 + threadIdx.x;
  int row = ch >> 6, seg = ch & 63;
  int b = row & 31, t = row >> 5;
  int idx = x[b * 256 + t];
  const float* s = emb + (size_t)idx * 512 + seg * 8;
  float4 f0 = *(const float4*)(s);
  float4 f1 = *(const float4*)(s + 4);
  __hip_bfloat16 h[8];
  h[0] = __float2bfloat16(f0.x); h[1] = __float2bfloat16(f0.y);
  h[2] = __float2bfloat16(f0.z); h[3] = __float2bfloat16(f0.w);
  h[4] = __float2bfloat16(f1.x); h[5] = __float2bfloat16(f1.y);
  h[6] = __float2bfloat16(f1.z); h[7] = __float2bfloat16(f1.w);
  *(uint4*)(A + (size_t)row * 512 + seg * 8) = *(const uint4*)h;
}

__global__ __launch_bounds__(256) void init_h(const float* __restrict__ h0f,
                                              const float* __restrict__ h0b,
                                              __hip_bfloat16* __restrict__ h16,
                                              unsigned* __restrict__ flags) {
  int i = blockIdx.x * 256 + threadIdx.x;
  int d = i >> 15, j = i & 32767;
  float v = d ? h0b[j] : h0f[j];
  h16[i] = __float2bfloat16(v);
  if (i < 128) flags[i * 16] = 0u;   // 64B-strided flag lines
}

// ---------------- big GEMM: xW[8192][6144] = A[8192][512] @ WT[6144][512]^T ----------------
__global__ __launch_bounds__(256) void gemm_xw(const __hip_bfloat16* __restrict__ A,
                                               const __hip_bfloat16* __restrict__ B,
                                               __hip_bfloat16* __restrict__ C) {
  __shared__ char sm[2 * 128 * 80];
  const int tid = threadIdx.x;
  const int bn = blockIdx.x, bm = blockIdx.y;
  const int l = tid & 63, w = tid >> 6;
  const int wm = w & 1, wn = w >> 1;
  const int lr = l & 15, lk = l >> 4;
  f32x4 acc[4][4] = {};
  for (int k0 = 0; k0 < 512; k0 += 32) {
    __syncthreads();
#pragma unroll
    for (int i = 0; i < 2; ++i) {
      int ch = tid + i * 256;
      int row = ch >> 2, kq = ch & 3;
      uint4 va = *(const uint4*)(A + (size_t)(bm * 128 + row) * 512 + k0 + kq * 8);
      *(uint4*)(sm + row * 80 + kq * 16) = va;
      uint4 vb = *(const uint4*)(B + (size_t)(bn * 128 + row) * 512 + k0 + kq * 8);
      *(uint4*)(sm + 10240 + row * 80 + kq * 16) = vb;
    }
    __syncthreads();
    bf16x8 af[4], bfr[4];
#pragma unroll
    for (int m = 0; m < 4; ++m)
      af[m] = *(const bf16x8*)(sm + (wm * 64 + m * 16 + lr) * 80 + lk * 16);
#pragma unroll
    for (int n = 0; n < 4; ++n)
      bfr[n] = *(const bf16x8*)(sm + 10240 + (wn * 64 + n * 16 + lr) * 80 + lk * 16);
#pragma unroll
    for (int m = 0; m < 4; ++m)
#pragma unroll
      for (int n = 0; n < 4; ++n)
        acc[m][n] = mfma_bf16(af[m], bfr[n], acc[m][n]);
  }
#pragma unroll
  for (int m = 0; m < 4; ++m)
#pragma unroll
    for (int n = 0; n < 4; ++n)
#pragma unroll
      for (int v = 0; v < 4; ++v) {
        int row = bm * 128 + wm * 64 + m * 16 + lk * 4 + v;
        int col = bn * 128 + wn * 64 + n * 16 + lr;
        C[(size_t)row * 6144 + col] = __float2bfloat16(acc[m][n][v]);
      }
}

// ---------------- persistent GRU recurrence ----------------
// grid = 128 blocks: blockIdx.x = colblk*2 + dir; 512 threads = 8 waves:
// wave w -> (m = w&1, q = w>>1): batch-half m, K-quarter q, ALL 3 gates.
// U: 24 bf16x8 fragments per wave, asm-pinned in VGPRs.
// Barrier: per-block flag lines (64B apart), wave 0 polls, others wait in s_barrier.
__global__ __launch_bounds__(512, 2) void gru_persist(
    const __hip_bfloat16* __restrict__ xW,
    const __hip_bfloat16* __restrict__ UT,
    const float* __restrict__ bias_f,
    const float* __restrict__ bias_b,
    const float* __restrict__ h0_f,
    const float* __restrict__ h0_b,
    __hip_bfloat16* H16,        // [2 buffers][2 dirs][32][1024]
    unsigned* flags,            // [2 dirs][64 blocks] x 64B stride
    float* __restrict__ out) {
  __shared__ float xacc[3][2][3][16][17];   // [q-1][m][g][row][col+pad]

  const int tid = threadIdx.x;
  const int l = tid & 63, w = tid >> 6;
  const int m = w & 1, q = w >> 1;
  const int dir = blockIdx.x & 1;
  const int cb = blockIdx.x >> 1;           // col-block 0..63
  const int c0 = cb * 16;
  const int lr = l & 15, lk = l >> 4;
  const int col = c0 + lr;

  // ---- pin U fragments: gates 0..2, K-slice q*256..q*256+256 ----
  bf16x8 ub[3][8];
  {
#pragma unroll
    for (int g = 0; g < 3; ++g) {
      const __hip_bfloat16* Urow =
          UT + (size_t)(dir * 3072 + g * 1024 + col) * 1024 + q * 256 + lk * 8;
#pragma unroll
      for (int kc = 0; kc < 8; ++kc) ub[g][kc] = ld_b128(Urow + kc * 32);
    }
    WAITV(0);
    __builtin_amdgcn_sched_barrier(0);
  }

  const float* bias = dir ? bias_b : bias_f;
  const float b0z = bias[col],        b0r = bias[1024 + col], b0n = bias[2048 + col];
  const float b1z = bias[3072 + col], b1r = bias[4096 + col], b1n = bias[5120 + col];

  float hp[4];
  {
    const float* h0 = dir ? h0_b : h0_f;
#pragma unroll
    for (int v = 0; v < 4; ++v)
      hp[v] = h0[(m * 16 + lk * 4 + v) * 1024 + col];
  }

  for (int s = 0; s < 256; ++s) {
    const __hip_bfloat16* hin  = H16 + (size_t)(s & 1) * 65536 + dir * 32768;
    __hip_bfloat16*       hout = H16 + (size_t)((s & 1) ^ 1) * 65536 + dir * 32768;
    const int t = dir ? (255 - s) : s;

    // ---- issue xW loads FIRST (combiner waves q==0 only; wave-uniform branch) ----
    unsigned xwv[12];
    if (q == 0) {
      const __hip_bfloat16* xp =
          xW + (size_t)(t * 32 + m * 16) * 6144 + dir * 3072 + col;
#pragma unroll
      for (int v = 0; v < 4; ++v)
#pragma unroll
        for (int gg = 0; gg < 3; ++gg)
          xwv[v * 3 + gg] = ld_u16(xp + (size_t)(lk * 4 + v) * 6144 + gg * 1024);
    }

    // ---- issue ALL 8 h loads (coherent), then wait-ladder + MFMA ----
    // vmcnt retires oldest-first, so waiting vmcnt(7-kc) works for both branches.
    const __hip_bfloat16* hrow = hin + (size_t)(m * 16 + lr) * 1024 + q * 256 + lk * 8;
    bf16x8 hb[8];
#pragma unroll
    for (int kc = 0; kc < 8; ++kc) hb[kc] = ld_sys_b128(hrow + kc * 32);

    f32x4 a0 = {}, a1 = {}, a2 = {};
#define KSTEP(kc, n)                                           \
    WAITV(n);                                                  \
    __builtin_amdgcn_sched_barrier(0);                         \
    a0 = mfma_bf16(hb[kc], ub[0][kc], a0);                     \
    a1 = mfma_bf16(hb[kc], ub[1][kc], a1);                     \
    a2 = mfma_bf16(hb[kc], ub[2][kc], a2);
    KSTEP(0, 7) KSTEP(1, 6) KSTEP(2, 5) KSTEP(3, 4)
    KSTEP(4, 3) KSTEP(5, 2) KSTEP(6, 1) KSTEP(7, 0)
#undef KSTEP

    // ---- partial-sum exchange: q=1..3 write, q=0 combines ----
    if (q) {
#pragma unroll
      for (int v = 0; v < 4; ++v) {
        xacc[q - 1][m][0][lk * 4 + v][lr] = a0[v];
        xacc[q - 1][m][1][lk * 4 + v][lr] = a1[v];
        xacc[q - 1][m][2][lk * 4 + v][lr] = a2[v];
      }
    }
    __syncthreads();
    if (q == 0) {
#pragma unroll
      for (int v = 0; v < 4; ++v) {
        const int row = lk * 4 + v;
        const int b = m * 16 + row;
        float hUz = a0[v], hUr = a1[v], hUn = a2[v];
#pragma unroll
        for (int qq = 0; qq < 3; ++qq) {
          hUz += xacc[qq][m][0][row][lr];
          hUr += xacc[qq][m][1][row][lr];
          hUn += xacc[qq][m][2][row][lr];
        }
        const float xz = bf2f(xwv[v * 3 + 0]);
        const float xr = bf2f(xwv[v * 3 + 1]);
        const float xn = bf2f(xwv[v * 3 + 2]);
        const float z = 1.f / (1.f + expf(-(xz + b0z + hUz + b1z)));
        const float r = 1.f / (1.f + expf(-(xr + b0r + hUr + b1r)));
        const float n = tanhf(xn + b0n + r * (hUn + b1n));
        const float hn = z * hp[v] + (1.f - z) * n;
        hp[v] = hn;
        out[((size_t)b * 256 + t) * 2048 + dir * 1024 + col] = hn;
        st_sys_u16(hout + (size_t)b * 1024 + col,
                   (unsigned)__builtin_bit_cast(unsigned short, __float2bfloat16(hn)));
        if (s == 255) out[16777216 + dir * 32768 + b * 1024 + col] = hn;
      }
      WAITV(0);   // drain h stores to coherence point before flag
    }
    __syncthreads();
    if (tid == 0) st_sys_u32(flags + (dir * 64 + cb) * 16, (unsigned)(s + 1));
    if (w == 0) {
      const unsigned* fl = flags + (dir * 64 + l) * 16;   // lane l polls block l of dir
      const unsigned tgt = (unsigned)(s + 1);
      for (;;) {
        unsigned v = ld_sys_u32(fl);
        WAITV(0);
        if (__all(v >= tgt)) break;
        __builtin_amdgcn_s_sleep(1);
      }
    }
    __syncthreads();
  }
}

// ---------------- host ----------------

extern "C" void kernel_launch(void* const* d_in, const int* in_sizes, int n_in,
                              void* d_out, int out_size, void* d_ws, size_t ws_size,
                              hipStream_t stream) {
  const int*   x    = (const int*)d_in[0];
  const float* emb  = (const float*)d_in[1];
  const float* W_f  = (const float*)d_in[2];
  const float* U_f  = (const float*)d_in[3];
  const float* b_f  = (const float*)d_in[4];
  const float* W_b  = (const float*)d_in[5];
  const float* U_b  = (const float*)d_in[6];
  const float* b_b  = (const float*)d_in[7];
  const float* h0_f = (const float*)d_in[8];
  const float* h0_b = (const float*)d_in[9];
  float* out = (float*)d_out;
  char* ws = (char*)d_ws;

  const size_t SZ_A  = (size_t)8192 * 512 * 2;
  const size_t SZ_WT = (size_t)6144 * 512 * 2;
  const size_t SZ_UT = (size_t)6144 * 1024 * 2;
  const size_t SZ_XW = (size_t)8192 * 6144 * 2;
  const size_t SZ_H  = (size_t)2 * 65536 * 2;

  __hip_bfloat16* A   = (__hip_bfloat16*)(ws);
  __hip_bfloat16* WT  = (__hip_bfloat16*)(ws + SZ_A);
  __hip_bfloat16* UT  = (__hip_bfloat16*)(ws + SZ_A + SZ_WT);
  __hip_bfloat16* XW  = (__hip_bfloat16*)(ws + SZ_A + SZ_WT + SZ_UT);
  __hip_bfloat16* H16 = (__hip_bfloat16*)(ws + SZ_A + SZ_WT + SZ_UT + SZ_XW);
  unsigned*       FLG = (unsigned*)(ws + SZ_A + SZ_WT + SZ_UT + SZ_XW + SZ_H);

  transpose_cast<<<dim3(96, 16), 256, 0, stream>>>(W_f, WT, 512, 3072);
  transpose_cast<<<dim3(96, 16), 256, 0, stream>>>(W_b, WT + (size_t)3072 * 512, 512, 3072);
  transpose_cast<<<dim3(96, 32), 256, 0, stream>>>(U_f, UT, 1024, 3072);
  transpose_cast<<<dim3(96, 32), 256, 0, stream>>>(U_b, UT + (size_t)3072 * 1024, 1024, 3072);
  gather_embed<<<2048, 256, 0, stream>>>(x, emb, A);
  init_h<<<256, 256, 0, stream>>>(h0_f, h0_b, H16, FLG);

  gemm_xw<<<dim3(48, 64), 256, 0, stream>>>(A, WT, XW);

  void* args[] = {(void*)&XW, (void*)&UT, (void*)&b_f, (void*)&b_b,
                  (void*)&h0_f, (void*)&h0_b, (void*)&H16, (void*)&FLG, (void*)&out};
  hipLaunchCooperativeKernel((void*)gru_persist, dim3(128), dim3(512),
                             args, 0, stream);
}